// Round 1
// 328.427 us; speedup vs baseline: 1.2041x; 1.2041x over previous
//
#include <hip/hip_runtime.h>

#define NPTS 8192
#define NCH 8
#define STRIDE 6144
#define TOTAL 51200
#define FADE 1228
#define SEG 32
#define SEGLEN 256   // NPTS / SEG
#define JB 4         // j's per thread in argmin
#define TEAMS 4      // t-range teams per argmin block
#define TLEN 64      // SEGLEN / TEAMS

// ---------------------------------------------------------------------------
// copy ALL chunks -> fin (chunk i pre-filled so smoother epilogue only writes
// winner rows), init jmax to -1, init packed argmin buffers to all-ones.
__global__ void k_setup(const float* __restrict__ chunks, float* __restrict__ fin,
                        int* __restrict__ jmax_all, unsigned int* __restrict__ packed32) {
    int i = blockIdx.x * 256 + threadIdx.x;            // grid covers 196608
    if (i < NCH * NPTS * 3) fin[i] = chunks[i];
    if (i < (NCH - 1) * NPTS) jmax_all[i] = -1;
    if (i < (NCH - 1) * NPTS * 2) packed32[i] = 0xFFFFFFFFu;
}

// ---------------------------------------------------------------------------
// Brute-force argmin over a 256-candidate segment, JB=4 queries per thread.
// d chain bit-identical to round 2: g = fma(p2,cz, fma(p1,cy, p0*cx));
// sadd = pp + cc; d = fma(-2, g, sadd)  [== (pp+cc) - 2g, single rounding].
//
// NEW: 1024-thread blocks = 4 teams x 256 threads. All teams handle the SAME
// 1024 j's; team q scans t in [q*64, q*64+64) ascending with strict < (lowest
// t wins ties within the team). Teams 1-3 publish packed (mapped_d<<32 | k)
// to LDS; team 0 u64-mins across teams (equal d bits -> lowest k, identical
// to a full ascending strict-< scan) and issues the one global atomicMin.
// Grid (8,32) = 256 blocks = 1 block/CU -> 16 waves/CU = 4 waves/SIMD
// (was 1 wave/SIMD), hiding ds_read + select-chain latency.
__global__ __launch_bounds__(1024) void k_argmin(const float* __restrict__ P,
                                                 const float* __restrict__ C,
                                                 unsigned long long* __restrict__ packed) {
#pragma clang fp contract(off)
    __shared__ float4 sh[SEGLEN];
    __shared__ unsigned long long pkbuf[TEAMS - 1][1024];
    int tid = threadIdx.x;
    int lt   = tid & 255;          // lane within team (0..255)
    int team = tid >> 8;           // 0..3
    int k0 = blockIdx.y * SEGLEN;
    if (tid < SEGLEN) {
        int k = k0 + tid;
        float x = C[k * 3 + 0], y = C[k * 3 + 1], z = C[k * 3 + 2];
        float cc = (x * x + y * y) + z * z;
        sh[tid] = make_float4(x, y, z, cc);
    }
    __syncthreads();
    int j0 = blockIdx.x * (256 * JB) + lt * JB;
    const float4* Pv = (const float4*)(P + j0 * 3);    // 12 floats, 16B-aligned
    float4 a = Pv[0], b = Pv[1], c4 = Pv[2];
    float p0[JB] = {a.x, a.w, b.z, c4.y};
    float p1[JB] = {a.y, b.x, b.w, c4.z};
    float p2[JB] = {a.z, b.y, c4.x, c4.w};
    float pp[JB], best[JB];
    int bt[JB];
    int t0 = team * TLEN;
#pragma unroll
    for (int i = 0; i < JB; ++i) {
        pp[i] = (p0[i] * p0[i] + p1[i] * p1[i]) + p2[i] * p2[i];
        best[i] = 3.4e38f;
        bt[i] = t0;
    }
#pragma unroll 4
    for (int tt = 0; tt < TLEN; ++tt) {
        int t = t0 + tt;
        float4 f = sh[t];
#pragma unroll
        for (int i = 0; i < JB; ++i) {
            float g = __builtin_fmaf(p2[i], f.z, __builtin_fmaf(p1[i], f.y, p0[i] * f.x));
            float sadd = pp[i] + f.w;
            float d = __builtin_fmaf(-2.0f, g, sadd);
            if (d < best[i]) { best[i] = d; bt[i] = t; }   // strict <: lowest t wins ties
        }
    }
    unsigned long long pk[JB];
#pragma unroll
    for (int i = 0; i < JB; ++i) {
        unsigned ud = __float_as_uint(best[i]);
        if (ud == 0x80000000u) ud = 0u;                 // canonicalize -0 -> +0 (bitwise)
        ud = (ud & 0x80000000u) ? ~ud : (ud | 0x80000000u);   // order-preserving map
        pk[i] = ((unsigned long long)ud << 32)
              | (unsigned long long)(unsigned)(k0 + bt[i]);
    }
    if (team > 0) {
#pragma unroll
        for (int i = 0; i < JB; ++i) pkbuf[team - 1][lt * JB + i] = pk[i];
    }
    __syncthreads();
    if (team == 0) {
#pragma unroll
        for (int i = 0; i < JB; ++i) {
            unsigned long long v = pk[i];
            unsigned long long v1 = pkbuf[0][lt * JB + i];
            unsigned long long v2 = pkbuf[1][lt * JB + i];
            unsigned long long v3 = pkbuf[2][lt * JB + i];
            if (v1 < v) v = v1;
            if (v2 < v) v = v2;
            if (v3 < v) v = v3;
            atomicMin(&packed[j0 + i], v);
        }
    }
}

// ---------------------------------------------------------------------------
// unpack match index + weight-predictor MLP (weights in LDS) + fused-combine
// + deduped jmax atomicMax. 64 blocks x 128 threads, one query per thread.
__global__ __launch_bounds__(128) void k_resolve(
        const float* __restrict__ P, const float* __restrict__ C,
        const unsigned long long* __restrict__ packed,
        const float* __restrict__ w1g, const float* __restrict__ b1g,
        const float* __restrict__ w2g, const float* __restrict__ b2g,
        const float* __restrict__ w3g, const float* __restrict__ b3g,
        float* __restrict__ fused, int* __restrict__ mi, int* __restrict__ jmax) {
#pragma clang fp contract(off)
    __shared__ float W[780];   // w1[0:192) b1[192:224) w2[224:736) b2[736:752) w3[752:768) b3[768]
    int tid = threadIdx.x;
    for (int i = tid; i < 780; i += 128) {
        float v;
        if (i < 192) v = w1g[i];
        else if (i < 224) v = b1g[i - 192];
        else if (i < 736) v = w2g[i - 224];
        else if (i < 752) v = b2g[i - 736];
        else if (i < 768) v = w3g[i - 752];
        else v = b3g[0];
        W[i] = v;
    }
    __syncthreads();

    int j = blockIdx.x * 128 + tid;
    int m = (int)(unsigned)(packed[j] & 0xFFFFFFFFull);
    mi[j] = m;
    float x6[6];
    x6[0] = P[j * 3 + 0]; x6[1] = P[j * 3 + 1]; x6[2] = P[j * 3 + 2];
    x6[3] = C[m * 3 + 0]; x6[4] = C[m * 3 + 1]; x6[5] = C[m * 3 + 2];

    float h1[32];
#pragma unroll
    for (int o = 0; o < 32; ++o) {
        float acc = 0.0f;
#pragma unroll
        for (int ci = 0; ci < 6; ++ci) acc = __builtin_fmaf(x6[ci], W[o * 6 + ci], acc);
        h1[o] = fmaxf(acc + W[192 + o], 0.0f);
    }
    float h2[16];
#pragma unroll
    for (int o = 0; o < 16; ++o) {
        float acc = 0.0f;
#pragma unroll
        for (int ci = 0; ci < 32; ++ci) acc = __builtin_fmaf(h1[ci], W[224 + o * 32 + ci], acc);
        h2[o] = fmaxf(acc + W[736 + o], 0.0f);
    }
    float acc = 0.0f;
#pragma unroll
    for (int ci = 0; ci < 16; ++ci) acc = __builtin_fmaf(h2[ci], W[752 + ci], acc);
    float z = acc + W[768];
    float w = 1.0f / (1.0f + expf(-z));
    float omw = 1.0f - w;
#pragma unroll
    for (int e = 0; e < 3; ++e) {
        float t1 = w * x6[e];
        float t2 = omw * x6[3 + e];
        fused[e * NPTS + j] = t1 + t2;
    }

    // wave-level dedupe: only the highest-j lane per distinct m issues the atomic
    int lane = tid & 63;
    bool issue = true;
    for (int s = 1; s < 64; ++s) {
        int om = __shfl_down(m, s);
        if (lane + s < 64 && om == m) issue = false;
    }
    if (issue) atomicMax(&jmax[m], j);
}

// ---------------------------------------------------------------------------
// fused boundary smoother (round-2 verified body) + fused scatter epilogue:
// winners write fin_next[k] directly (fin_next pre-filled with raw chunk).
#define S1 41
#define S2 37
__global__ __launch_bounds__(256) void k_smoother(const float* __restrict__ fused,
        const float* __restrict__ w1g, const float* __restrict__ b1g,
        const float* __restrict__ w2g, const float* __restrict__ b2g,
        const float* __restrict__ w3g, const float* __restrict__ b3g,
        float* __restrict__ sm, const int* __restrict__ mi,
        const int* __restrict__ jmax, float* __restrict__ finNext) {
#pragma clang fp contract(off)
    __shared__ float F[3][44];
    __shared__ float H1[32][S1];
    __shared__ float H2[32][S2];
    __shared__ float W2[5120];
    __shared__ float B2[32];
    int tid = threadIdx.x;
    int BASE = blockIdx.x * 32;

    for (int li = tid; li < 132; li += 256) {
        int c = li / 44, i = li % 44;
        int t = BASE - 6 + i;
        F[c][i] = (t >= 0 && t < NPTS) ? fused[c * NPTS + t] : 0.0f;
    }
    for (int li = tid; li < 1280; li += 256) {
        float4 v = ((const float4*)w2g)[li];
        int base = li * 4;
#pragma unroll
        for (int u = 0; u < 4; ++u) {
            int idx = base + u;
            int co = idx / 160;
            int r = idx - co * 160;
            int ci = r / 5;
            int k = r - ci * 5;
            W2[(ci * 5 + k) * 32 + co] = (&v.x)[u];
        }
    }
    if (tid < 32) B2[tid] = b2g[tid];
    __syncthreads();

    {
        int co = tid >> 3, pg = tid & 7;
        float wr[15];
#pragma unroll
        for (int q = 0; q < 15; ++q) wr[q] = w1g[co * 15 + q];
        float bias = b1g[co];
#pragma unroll
        for (int s = 0; s < 5; ++s) {
            int i = pg * 5 + s;
            int t = BASE - 4 + i;
            float acc = 0.0f;
#pragma unroll
            for (int k = 0; k < 5; ++k)
#pragma unroll
                for (int ci = 0; ci < 3; ++ci)
                    acc = __builtin_fmaf(F[ci][i + k], wr[ci * 5 + k], acc);
            H1[co][i] = (t >= 0 && t < NPTS) ? fmaxf(acc + bias, 0.0f) : 0.0f;
        }
    }
    __syncthreads();

    {
        int cq = tid & 7, pp = tid >> 3;
        if (pp < 18) {
            int i2 = pp * 2;
            int co0 = cq * 4;
            float acc00 = 0.f, acc01 = 0.f, acc02 = 0.f, acc03 = 0.f;
            float acc10 = 0.f, acc11 = 0.f, acc12 = 0.f, acc13 = 0.f;
            for (int k = 0; k < 5; ++k) {
#pragma unroll
                for (int ci = 0; ci < 32; ++ci) {
                    float in0 = H1[ci][i2 + k];
                    float in1 = H1[ci][i2 + k + 1];
                    const float4 wv = *(const float4*)&W2[(ci * 5 + k) * 32 + co0];
                    acc00 = __builtin_fmaf(in0, wv.x, acc00);
                    acc01 = __builtin_fmaf(in0, wv.y, acc01);
                    acc02 = __builtin_fmaf(in0, wv.z, acc02);
                    acc03 = __builtin_fmaf(in0, wv.w, acc03);
                    acc10 = __builtin_fmaf(in1, wv.x, acc10);
                    acc11 = __builtin_fmaf(in1, wv.y, acc11);
                    acc12 = __builtin_fmaf(in1, wv.z, acc12);
                    acc13 = __builtin_fmaf(in1, wv.w, acc13);
                }
            }
            int t0 = BASE - 2 + i2, t1 = t0 + 1;
            bool ok0 = (t0 >= 0 && t0 < NPTS), ok1 = (t1 >= 0 && t1 < NPTS);
            H2[co0 + 0][i2]     = ok0 ? fmaxf(acc00 + B2[co0 + 0], 0.0f) : 0.0f;
            H2[co0 + 1][i2]     = ok0 ? fmaxf(acc01 + B2[co0 + 1], 0.0f) : 0.0f;
            H2[co0 + 2][i2]     = ok0 ? fmaxf(acc02 + B2[co0 + 2], 0.0f) : 0.0f;
            H2[co0 + 3][i2]     = ok0 ? fmaxf(acc03 + B2[co0 + 3], 0.0f) : 0.0f;
            H2[co0 + 0][i2 + 1] = ok1 ? fmaxf(acc10 + B2[co0 + 0], 0.0f) : 0.0f;
            H2[co0 + 1][i2 + 1] = ok1 ? fmaxf(acc11 + B2[co0 + 1], 0.0f) : 0.0f;
            H2[co0 + 2][i2 + 1] = ok1 ? fmaxf(acc12 + B2[co0 + 2], 0.0f) : 0.0f;
            H2[co0 + 3][i2 + 1] = ok1 ? fmaxf(acc13 + B2[co0 + 3], 0.0f) : 0.0f;
        }
    }
    __syncthreads();

    if (tid < 96) {
        int co = tid >> 5, p = tid & 31;
        float wr[160];
        const float4* w3v = (const float4*)(w3g + co * 160);
#pragma unroll
        for (int q = 0; q < 40; ++q) {
            float4 v = w3v[q];
            wr[q * 4 + 0] = v.x; wr[q * 4 + 1] = v.y;
            wr[q * 4 + 2] = v.z; wr[q * 4 + 3] = v.w;
        }
        float acc = 0.0f;
#pragma unroll
        for (int k = 0; k < 5; ++k)
#pragma unroll
            for (int ci = 0; ci < 32; ++ci)
                acc = __builtin_fmaf(H2[ci][p + k], wr[ci * 5 + k], acc);
        float val = acc + b3g[co];
        int jj = BASE + p;
        sm[jj * 3 + co] = val;
        // fused scatter: unique winner j per k (jmax finalized in k_resolve)
        int kk = mi[jj];
        if (jmax[kk] == jj) finNext[kk * 3 + co] = val;
    }
}

// ---------------------------------------------------------------------------
__global__ void k_merge(const float* __restrict__ fin, float* __restrict__ out) {
#pragma clang fp contract(off)
    int pos = blockIdx.x * 256 + threadIdx.x;
    if (pos >= TOTAL) return;
    int imax = pos / STRIDE; if (imax > NCH - 1) imax = NCH - 1;
    int imin = (pos >= NPTS) ? ((pos - NPTS) / STRIDE + 1) : 0;
    float a0 = 0.0f, a1 = 0.0f, a2 = 0.0f, wsum = 0.0f;
    const float kstep = 0.9f / 1227.0f;
    for (int i = imin; i <= imax; ++i) {
        int t = pos - i * STRIDE;
        float cw;
        if (t < FADE)                cw = 0.1f + (float)t * kstep;
        else if (t >= NPTS - FADE)   cw = 1.0f - (float)(t - (NPTS - FADE)) * kstep;
        else                         cw = 1.0f;
        const float* v = fin + (i * NPTS + t) * 3;
        a0 += cw * v[0];
        a1 += cw * v[1];
        a2 += cw * v[2];
        wsum += cw;
    }
    float wm = fmaxf(wsum, 1e-8f);
    out[pos * 3 + 0] = a0 / wm;
    out[pos * 3 + 1] = a1 / wm;
    out[pos * 3 + 2] = a2 / wm;
}

// ---------------------------------------------------------------------------
extern "C" void kernel_launch(void* const* d_in, const int* in_sizes, int n_in,
                              void* d_out, int out_size, void* d_ws, size_t ws_size,
                              hipStream_t stream) {
    const float* chunks = (const float*)d_in[0];
    const float* bs_w1 = (const float*)d_in[1];
    const float* bs_b1 = (const float*)d_in[2];
    const float* bs_w2 = (const float*)d_in[3];
    const float* bs_b2 = (const float*)d_in[4];
    const float* bs_w3 = (const float*)d_in[5];
    const float* bs_b3 = (const float*)d_in[6];
    const float* wp_w1 = (const float*)d_in[7];
    const float* wp_b1 = (const float*)d_in[8];
    const float* wp_w2 = (const float*)d_in[9];
    const float* wp_b2 = (const float*)d_in[10];
    const float* wp_w3 = (const float*)d_in[11];
    const float* wp_b3 = (const float*)d_in[12];

    unsigned long long* packed_all = (unsigned long long*)d_ws;   // 7*8192 u64 (8B-aligned base)
    float* fin      = (float*)(packed_all + (NCH - 1) * NPTS);    // 196608 f32
    float* fused    = fin + NCH * NPTS * 3;                       // 24576 f32
    int*   mi       = (int*)(fused + 3 * NPTS);                   // 8192 i32
    int*   jmax_all = mi + NPTS;                                  // 57344 i32
    // total ~1.6 MB

    k_setup<<<768, 256, 0, stream>>>(chunks, fin, jmax_all, (unsigned int*)packed_all);

    for (int i = 1; i < NCH; ++i) {
        const float* C = chunks + i * NPTS * 3;
        float* P  = fin + (i - 1) * NPTS * 3;
        float* Pn = fin + i * NPTS * 3;
        unsigned long long* packed = packed_all + (i - 1) * NPTS;
        int* jmax = jmax_all + (i - 1) * NPTS;

        k_argmin<<<dim3(NPTS / (256 * JB), SEG), 1024, 0, stream>>>(P, C, packed);
        k_resolve<<<64, 128, 0, stream>>>(P, C, packed, wp_w1, wp_b1, wp_w2, wp_b2,
                                          wp_w3, wp_b3, fused, mi, jmax);
        k_smoother<<<256, 256, 0, stream>>>(fused, bs_w1, bs_b1, bs_w2, bs_b2,
                                            bs_w3, bs_b3, P, mi, jmax, Pn);
    }

    k_merge<<<200, 256, 0, stream>>>(fin, (float*)d_out);
}